// Round 7
// baseline (216.578 us; speedup 1.0000x reference)
//
#include <hip/hip_runtime.h>

#define NLOCAL 55000
#define NOWNED 50000
#define NEDGES 800000
#define INC 128
#define HIDC 128
#define OUTC 64
#define CAP 64            // padded-CSR bucket capacity (max degree; P(exceed) ~ 1e-15)
#define CNTS 16           // cnt stride in ints (one counter per 64B line: kills L2 RMW contention)
#define NSTRIPS (NOWNED / 16)   // 3125 exact
#define ZLD 136           // zt LDS row stride in shorts (+8 pad: phase-B ds_read 2-way/free)

typedef unsigned short ushort_t;
typedef unsigned int uint_t;
typedef short short8_t __attribute__((ext_vector_type(8)));
typedef float float4_t __attribute__((ext_vector_type(4)));

static __device__ __forceinline__ ushort_t f2bf(float f) {   // RNE fp32->bf16
    uint_t u = __float_as_uint(f);
    return (ushort_t)((u + 0x7FFFu + ((u >> 16) & 1u)) >> 16);
}
static __device__ __forceinline__ float bflo(uint_t v) { return __uint_as_float(v << 16); }
static __device__ __forceinline__ float bfhi(uint_t v) { return __uint_as_float(v & 0xFFFF0000u); }

// ======= prep (fused): xd = bf16(deg*x); zero cnt; transpose w1,w2 to bf16 [n][k] =======
__global__ __launch_bounds__(256) void prep_k(const float* __restrict__ x,
                                              const float* __restrict__ deg,
                                              const float* __restrict__ w1,
                                              const float* __restrict__ w2,
                                              ushort_t* __restrict__ xd,
                                              ushort_t* __restrict__ w1t,
                                              ushort_t* __restrict__ w2t,
                                              int* __restrict__ cnt) {
    const int gid = blockIdx.x * 256 + threadIdx.x;
    if (gid < NLOCAL * 32) {                 // one float4 -> 4 bf16
        const int row = gid >> 5;
        const int c0 = (gid & 31) << 2;
        const float d = deg[row];
        const float4 v = *(const float4*)(x + (size_t)row * INC + c0);
        uint_t lo = (uint_t)f2bf(v.x * d) | ((uint_t)f2bf(v.y * d) << 16);
        uint_t hi = (uint_t)f2bf(v.z * d) | ((uint_t)f2bf(v.w * d) << 16);
        *(uint2*)(xd + (size_t)row * INC + c0) = make_uint2(lo, hi);
    }
    if (gid < NOWNED * CNTS) cnt[gid] = 0;   // padded counters (one per line)
    if (gid < HIDC * INC) {                  // w1 [K=128][N=128] -> w1t [N][K]
        const int k = gid >> 7, n = gid & 127;
        w1t[n * 128 + k] = f2bf(w1[gid]);
    } else if (gid < HIDC * INC + HIDC * OUTC) {   // w2 [K=128][N=64] -> w2t [N][K]
        const int j = gid - HIDC * INC;
        const int k = j >> 6, n = j & 63;
        w2t[n * 128 + k] = f2bf(w2[j]);
    }
}

// ================= padded-CSR build (ushort cols, line-padded counters) =================
__global__ __launch_bounds__(256) void fill_k(const int* __restrict__ er,
                                              const int* __restrict__ ec,
                                              int* __restrict__ cnt,
                                              ushort_t* __restrict__ cols_pad) {
    const int e = blockIdx.x * 256 + threadIdx.x;
    if (e >= NEDGES) return;
    const int row = er[e];
    if (row >= NOWNED) return;                  // only owned destination rows matter
    const int p = atomicAdd(&cnt[row * CNTS], 1);
    if (p < CAP) cols_pad[row * CAP + p] = (ushort_t)ec[e];
}

// ========== layer-1 gather: agg1b[r] = bf16(sum_e xd[col])  (128 ch) ==========
// one wave per row; 4 edges/iter (16-lane quarters), uint4 = 8 ch/lane;
// wave-uniform scalar col loads (4 ushort cols per 8B), prefetched; fp32 acc, bf16 out
__global__ __launch_bounds__(256) void gather1_k(const ushort_t* __restrict__ xd,
                                                 const int* __restrict__ cnt,
                                                 const ushort_t* __restrict__ cols_pad,
                                                 ushort_t* __restrict__ agg1b) {
    const int w = __builtin_amdgcn_readfirstlane((blockIdx.x * 256 + threadIdx.x) >> 6);
    if (w >= NOWNED) return;
    const int lane = threadIdx.x & 63;
    const int q4 = lane >> 4;                   // quarter: edge 4j+q4
    const int ch = (lane & 15) << 3;            // 8 channels per lane (16 B)
    int n = cnt[w * CNTS];
    n = (n > CAP) ? CAP : n;
    const uint2* cp = (const uint2*)(cols_pad + w * CAP);   // 4 cols per 8B scalar load
    const int nIter = (n + 3) >> 2;
    float a0 = 0.f, a1 = 0.f, a2 = 0.f, a3 = 0.f, a4 = 0.f, a5 = 0.f, a6 = 0.f, a7 = 0.f;
    uint2 cc = (nIter > 0) ? cp[0] : make_uint2(0, 0);
    for (int j = 0; j < nIter; ++j) {
        const uint2 cn = cp[(j + 1 < 16) ? j + 1 : 15];    // prefetch next (clamped)
        const int e = j * 4 + q4;
        int myc = (q4 == 0) ? (int)(cc.x & 0xFFFF) :
                  (q4 == 1) ? (int)(cc.x >> 16) :
                  (q4 == 2) ? (int)(cc.y & 0xFFFF) : (int)(cc.y >> 16);
        const float wgt = (e < n) ? 1.f : 0.f;
        myc = (e < n) ? myc : 0;
        const uint4 v = *(const uint4*)(xd + (size_t)myc * INC + ch);
        a0 = fmaf(wgt, bflo(v.x), a0);  a1 = fmaf(wgt, bfhi(v.x), a1);
        a2 = fmaf(wgt, bflo(v.y), a2);  a3 = fmaf(wgt, bfhi(v.y), a3);
        a4 = fmaf(wgt, bflo(v.z), a4);  a5 = fmaf(wgt, bfhi(v.z), a5);
        a6 = fmaf(wgt, bflo(v.w), a6);  a7 = fmaf(wgt, bfhi(v.w), a7);
        cc = cn;
    }
    // fold the 4 quarters together
    a0 += __shfl_xor(a0, 16); a1 += __shfl_xor(a1, 16); a2 += __shfl_xor(a2, 16); a3 += __shfl_xor(a3, 16);
    a4 += __shfl_xor(a4, 16); a5 += __shfl_xor(a5, 16); a6 += __shfl_xor(a6, 16); a7 += __shfl_xor(a7, 16);
    a0 += __shfl_xor(a0, 32); a1 += __shfl_xor(a1, 32); a2 += __shfl_xor(a2, 32); a3 += __shfl_xor(a3, 32);
    a4 += __shfl_xor(a4, 32); a5 += __shfl_xor(a5, 32); a6 += __shfl_xor(a6, 32); a7 += __shfl_xor(a7, 32);
    if (lane < 16) {
        uint4 o;
        o.x = (uint_t)f2bf(a0) | ((uint_t)f2bf(a1) << 16);
        o.y = (uint_t)f2bf(a2) | ((uint_t)f2bf(a3) << 16);
        o.z = (uint_t)f2bf(a4) | ((uint_t)f2bf(a5) << 16);
        o.w = (uint_t)f2bf(a6) | ((uint_t)f2bf(a7) << 16);
        *(uint4*)(agg1b + (size_t)w * INC + ch) = o;
    }
}

// ===== fused gemm1+gemm2 (MFMA): h2 = bf16( relu(d*(agg1b@w1)+b1)*d @ w2 )  per 16-row strip =====
// block = 4 waves = one strip; gemm1 C-tile round-trips LDS (C-layout -> A-layout), feeds gemm2
__global__ __launch_bounds__(256) void gemm12_k(const ushort_t* __restrict__ agg1b,
                                                const ushort_t* __restrict__ w1t,
                                                const ushort_t* __restrict__ w2t,
                                                const float* __restrict__ b1,
                                                const float* __restrict__ deg,
                                                ushort_t* __restrict__ h2) {
    __shared__ ushort_t zt[16 * ZLD];           // 16 rows x 128 ch (+8 pad), 4.25 KB
    const int wv = threadIdx.x >> 6, lane = threadIdx.x & 63;
    const int strip = blockIdx.x;
    const int row0 = strip * 16;
    const int m = lane & 15, q = lane >> 4;

    // ---- phase A: z-tile = relu(d*(agg1b@w1)+b1)*d ; each wave does 2 of 8 n-tiles ----
    float4_t acc[2];
    acc[0] = (float4_t){0.f, 0.f, 0.f, 0.f};
    acc[1] = (float4_t){0.f, 0.f, 0.f, 0.f};
    #pragma unroll
    for (int ks = 0; ks < 4; ++ks) {
        const int k0 = ks * 32 + q * 8;
        const short8_t a = *(const short8_t*)(agg1b + (size_t)(row0 + m) * HIDC + k0);
        #pragma unroll
        for (int t = 0; t < 2; ++t) {
            const int nt = wv * 2 + t;
            const short8_t b = *(const short8_t*)(w1t + (size_t)(nt * 16 + m) * HIDC + k0);
            acc[t] = __builtin_amdgcn_mfma_f32_16x16x32_bf16(a, b, acc[t], 0, 0, 0);
        }
    }
    #pragma unroll
    for (int reg = 0; reg < 4; ++reg) {
        const int r = q * 4 + reg;              // row within strip
        const float d = deg[row0 + r];
        #pragma unroll
        for (int t = 0; t < 2; ++t) {
            const int col = (wv * 2 + t) * 16 + m;
            float v = fmaf(d, acc[t][reg], b1[col]);
            zt[r * ZLD + col] = f2bf(fmaxf(v, 0.f) * d);   // relu + fold layer-2 left d-scale
        }
    }
    __syncthreads();

    // ---- phase B: h2-tile = z @ w2 ; each wave does 1 of 4 n-tiles ----
    float4_t acc2 = (float4_t){0.f, 0.f, 0.f, 0.f};
    #pragma unroll
    for (int ks = 0; ks < 4; ++ks) {
        const int k0 = ks * 32 + q * 8;
        const short8_t a = *(const short8_t*)(&zt[m * ZLD + k0]);
        const short8_t b = *(const short8_t*)(w2t + (size_t)(wv * 16 + m) * HIDC + k0);
        acc2 = __builtin_amdgcn_mfma_f32_16x16x32_bf16(a, b, acc2, 0, 0, 0);
    }
    #pragma unroll
    for (int reg = 0; reg < 4; ++reg) {
        const int row = row0 + q * 4 + reg;
        h2[(size_t)row * OUTC + wv * 16 + m] = f2bf(acc2[reg]);
    }
}

// ===== layer-2 gather + epilogue: out[r] = deg[r]*sum(h2[col<NOWNED]) + b2 =====
// 4 edges/iter (quarters), uint2 = 4 ch/lane; scalar ushort-col loads w/ prefetch
__global__ __launch_bounds__(256) void gather2_k(const ushort_t* __restrict__ h2,
                                                 const float* __restrict__ deg,
                                                 const float* __restrict__ b2,
                                                 const int* __restrict__ cnt,
                                                 const ushort_t* __restrict__ cols_pad,
                                                 float* __restrict__ out) {
    const int w = __builtin_amdgcn_readfirstlane((blockIdx.x * 256 + threadIdx.x) >> 6);
    if (w >= NOWNED) return;
    const int lane = threadIdx.x & 63;
    const int q4 = lane >> 4;
    const int ch = (lane & 15) << 2;            // 4 channels per lane (8 B)
    int n = cnt[w * CNTS];
    n = (n > CAP) ? CAP : n;
    const uint2* cp = (const uint2*)(cols_pad + w * CAP);
    const int nIter = (n + 3) >> 2;
    float a0 = 0.f, a1 = 0.f, a2 = 0.f, a3 = 0.f;
    uint2 cc = (nIter > 0) ? cp[0] : make_uint2(0, 0);
    for (int j = 0; j < nIter; ++j) {
        const uint2 cn = cp[(j + 1 < 16) ? j + 1 : 15];
        const int e = j * 4 + q4;
        int myc = (q4 == 0) ? (int)(cc.x & 0xFFFF) :
                  (q4 == 1) ? (int)(cc.x >> 16) :
                  (q4 == 2) ? (int)(cc.y & 0xFFFF) : (int)(cc.y >> 16);
        const float wgt = (e < n && myc < NOWNED) ? 1.f : 0.f;  // halo rows of x2 are zero
        myc = (e < n && myc < NOWNED) ? myc : 0;
        const uint2 v = *(const uint2*)(h2 + (size_t)myc * OUTC + ch);
        a0 = fmaf(wgt, bflo(v.x), a0);  a1 = fmaf(wgt, bfhi(v.x), a1);
        a2 = fmaf(wgt, bflo(v.y), a2);  a3 = fmaf(wgt, bfhi(v.y), a3);
        cc = cn;
    }
    a0 += __shfl_xor(a0, 16); a1 += __shfl_xor(a1, 16); a2 += __shfl_xor(a2, 16); a3 += __shfl_xor(a3, 16);
    a0 += __shfl_xor(a0, 32); a1 += __shfl_xor(a1, 32); a2 += __shfl_xor(a2, 32); a3 += __shfl_xor(a3, 32);
    if (lane < 16) {
        const float d = deg[w];
        const float4 o = make_float4(fmaf(d, a0, b2[ch]),     fmaf(d, a1, b2[ch + 1]),
                                     fmaf(d, a2, b2[ch + 2]), fmaf(d, a3, b2[ch + 3]));
        *(float4*)(out + (size_t)w * OUTC + ch) = o;
    }
}

extern "C" void kernel_launch(void* const* d_in, const int* in_sizes, int n_in,
                              void* d_out, int out_size, void* d_ws, size_t ws_size,
                              hipStream_t stream) {
    const float* x   = (const float*)d_in[0];
    const float* deg = (const float*)d_in[1];
    const float* w1  = (const float*)d_in[2];
    const float* b1  = (const float*)d_in[3];
    const float* w2  = (const float*)d_in[4];
    const float* b2  = (const float*)d_in[5];
    const int* er    = (const int*)d_in[6];
    const int* ec    = (const int*)d_in[7];
    float* out = (float*)d_out;

    char* ws = (char*)d_ws;
    ushort_t* xd       = (ushort_t*)(ws);              // 14.08 MB [NLOCAL x 128] bf16
    ushort_t* cols_pad = (ushort_t*)(ws + 14090240);   // 6.4 MB   [NOWNED x CAP] ushort
    int* cnt           = (int*)(ws + 20490240);        // 3.2 MB   [NOWNED x CNTS] (line-padded)
    ushort_t* agg1b    = (ushort_t*)(ws + 23690240);   // 12.8 MB  [NOWNED x 128] bf16
    ushort_t* h2       = (ushort_t*)(ws + 36490240);   // 6.4 MB   [NOWNED x 64] bf16
    ushort_t* w1t      = (ushort_t*)(ws + 42890240);   // 32 KB    [128 x 128] bf16
    ushort_t* w2t      = (ushort_t*)(ws + 42923008);   // 16 KB    [64 x 128] bf16

    // prep (xd, w1t, w2t, cnt=0) -> CSR fill -> gather1 -> fused gemms -> gather2
    prep_k<<<(NLOCAL * 32 + 255) / 256, 256, 0, stream>>>(x, deg, w1, w2, xd, w1t, w2t, cnt);
    fill_k<<<(NEDGES + 255) / 256, 256, 0, stream>>>(er, ec, cnt, cols_pad);
    gather1_k<<<(NOWNED * 64 + 255) / 256, 256, 0, stream>>>(xd, cnt, cols_pad, agg1b);
    gemm12_k<<<NSTRIPS, 256, 0, stream>>>(agg1b, w1t, w2t, b1, deg, h2);
    gather2_k<<<(NOWNED * 64 + 255) / 256, 256, 0, stream>>>(h2, deg, b2, cnt, cols_pad, out);
}